// Round 10
// baseline (125.038 us; speedup 1.0000x reference)
//
#include <hip/hip_runtime.h>
#include <hip/hip_bf16.h>
#include <math.h>

#define BT 48
#define N 1024
#define F 64
#define CIN 64
#define EM 16
#define LRELU_A 0.2f
#define L2E 1.4426950408889634f

typedef short bf16x8 __attribute__((ext_vector_type(8)));   // 8 bf16 = 4 VGPRs
typedef float f32x4  __attribute__((ext_vector_type(4)));

// exact RTNE float->bf16 bits (off hot path)
__device__ __forceinline__ unsigned short f2bf(float f) {
    unsigned int u = __float_as_uint(f);
    return (unsigned short)((u + 0x7FFFu + ((u >> 16) & 1u)) >> 16);
}

// ------------------------------------------------------------------
// k_proj_misc (unchanged from round 7/9 — proven):
//  blocks 0..767: Wh row-block -> WhSw bf16 [bt][nb32][f][slot][j],
//    slot=(q+f)&3 XOR swizzle; + s1/s2 wave reductions.
//  blocks 768..895: adj bit-pack. blocks 896..899: f1/f2.
// ------------------------------------------------------------------
__global__ __launch_bounds__(256) void k_proj_misc(
    const float* __restrict__ x, const float* __restrict__ W,
    const float* __restrict__ a,
    const int* __restrict__ adj,
    const float* __restrict__ emb1, const float* __restrict__ emb2,
    const float* __restrict__ a2,
    unsigned short* __restrict__ WhSw,
    float* __restrict__ s1, float* __restrict__ s2,
    unsigned int* __restrict__ adjBits,
    float* __restrict__ f1, float* __restrict__ f2)
{
    const int tid = threadIdx.x;
    const int b   = blockIdx.x;

    if (b >= 768) {
        if (b < 896) {
            const int idx = (b - 768) * 256 + tid;
            const int r = idx >> 5, w32 = idx & 31;
            const int* p = adj + (size_t)r * N + w32 * 32;
            unsigned int m = 0;
#pragma unroll
            for (int j = 0; j < 32; ++j) m |= (p[j] > 0 ? 1u : 0u) << j;
            adjBits[idx] = m;
        } else {
            const int n = (b - 896) * 256 + tid;
            if (n < N) {
                float v1 = 0.f, v2 = 0.f;
#pragma unroll
                for (int k = 0; k < EM; ++k) {
                    v1 = fmaf(emb1[n * EM + k], a2[k], v1);
                    v2 = fmaf(emb2[n * EM + k], a2[EM + k], v2);
                }
                f1[n] = v1; f2[n] = v2;
            }
        }
        return;
    }

    __shared__ __align__(16) float sx[64 * 64];
    __shared__ __align__(16) float sWT[64 * 68];
    __shared__ __align__(16) unsigned short sT[64 * 80];

    const int bt  = b >> 4;
    const int n0  = (b & 15) * 64;
    const size_t grow = (size_t)bt * N + n0;

    {
        const float4* xv = (const float4*)(x + grow * CIN);
        float4* sxv = (float4*)sx;
        for (int i = tid; i < 64 * CIN / 4; i += 256) sxv[i] = xv[i];
        for (int i = tid; i < CIN * F; i += 256)
            sWT[(i & 63) * 68 + (i >> 6)] = W[i];
    }
    __syncthreads();

    const int f = tid & 63;
    const int w = tid >> 6;
    const float a1 = a[f], a2c = a[F + f];

    float acc[16];
#pragma unroll
    for (int t = 0; t < 16; ++t) acc[t] = 0.f;

    for (int cb = 0; cb < CIN; cb += 4) {
        const float4 wv = *(const float4*)&sWT[f * 68 + cb];
#pragma unroll
        for (int t = 0; t < 16; ++t) {
            const float4 xv = *(const float4*)&sx[(w * 16 + t) * 64 + cb];
            acc[t] = fmaf(xv.x, wv.x, acc[t]);
            acc[t] = fmaf(xv.y, wv.y, acc[t]);
            acc[t] = fmaf(xv.z, wv.z, acc[t]);
            acc[t] = fmaf(xv.w, wv.w, acc[t]);
        }
    }

#pragma unroll
    for (int t = 0; t < 16; ++t) {
        float v1 = acc[t] * a1;
        float v2 = acc[t] * a2c;
#pragma unroll
        for (int off = 32; off >= 1; off >>= 1) {
            v1 += __shfl_xor(v1, off, 64);
            v2 += __shfl_xor(v2, off, 64);
        }
        if (f == 0) {
            s1[grow + w * 16 + t] = v1;
            s2[grow + w * 16 + t] = v2;
        }
        sT[f * 80 + w * 16 + t] = f2bf(acc[t]);
    }
    __syncthreads();

    {
        const int ff = tid >> 2, q = tid & 3;
        const int slot = (q + ff) & 3;
        const int nb0 = (b & 15) * 2;
#pragma unroll
        for (int nbL = 0; nbL < 2; ++nbL) {
            const size_t dst = ((size_t)(bt * 32 + nb0 + nbL) * 64 + ff) * 32 + slot * 8;
            *(uint4*)&WhSw[dst] = *(const uint4*)&sT[ff * 80 + nbL * 32 + q * 8];
        }
    }
}

// ------------------------------------------------------------------
// k_attn round 10: round-9 structure (DMA double-buffer, XOR-swizzled
// B, factorized softmax, single barrier/chunk) + PACKED X:
//   sXP[j] = bf16(X2=2^.2c) << 16 | bf16(X1=2^c)  (one dword per col)
// A-side LDS reads halve (16 -> 8 b128 per wave per chunk); unpack is
// 2 full-rate ALU per col (shl / and). LDS traffic -22% overall.
// ------------------------------------------------------------------
__global__ __launch_bounds__(256, 3) void k_attn(
    const unsigned int* __restrict__ adjBits,
    const unsigned short* __restrict__ WhSw,
    const float* __restrict__ s1, const float* __restrict__ s2,
    const float* __restrict__ f1v, const float* __restrict__ f2v,
    float* __restrict__ out)
{
    __shared__ __align__(16) unsigned int sXP[N];           // 4 KB packed (X2,X1)
    __shared__ __align__(16) unsigned short sB[2][8192];    // 2 x 16 KB
    __shared__ float sWmax[4];

    const int tid  = threadIdx.x;
    const int xcd = blockIdx.x & 7;                         // XCD swizzle: 6 bt/XCD
    const int idx = blockIdx.x >> 3;
    const int bt  = xcd * 6 + (idx >> 4);
    const int i0  = (idx & 15) * 64;
    const int lane = tid & 63;
    const int w    = tid >> 6;
    const int q    = lane >> 4;
    const int m15  = lane & 15;

    // stage packed X and track block max of c (scaled by log2e)
    float cmax = -1e30f;
    for (int j = tid; j < N; j += 256) {
        const float c = (s2[bt * N + j] + f2v[j]) * L2E;
        const float X1 = exp2f(c);
        const float X2 = exp2f(LRELU_A * c);
        sXP[j] = ((unsigned int)f2bf(X2) << 16) | f2bf(X1);
        cmax = fmaxf(cmax, c);
    }
#pragma unroll
    for (int off = 32; off >= 1; off >>= 1) cmax = fmaxf(cmax, __shfl_xor(cmax, off, 64));
    if (lane == 0) sWmax[w] = cmax;
    __syncthreads();
    const float mx = fmaxf(fmaxf(sWmax[0], sWmax[1]), fmaxf(sWmax[2], sWmax[3]));

    const int growq = i0 + w * 16 + m15;
    const float r    = (s1[bt * N + growq] + f1v[growq]) * L2E;   // scaled domain
    const float smx  = r + mx;
    const float mhat = fmaxf(smx, LRELU_A * smx);           // >= every scaled e in row
    const float E1 = exp2f(r - mhat);
    const float E2 = exp2f(LRELU_A * r - mhat);
    const float T  = exp2f(-r);                             // X1 > T <=> c > -r
    float lsum = 0.f;

    const unsigned int* abRow = adjBits + growq * 32;
    const unsigned short* gBbt = WhSw + (size_t)bt * 65536;

    f32x4 acc[4];
#pragma unroll
    for (int ct = 0; ct < 4; ++ct)
#pragma unroll
        for (int e = 0; e < 4; ++e) acc[ct][e] = 0.f;

    auto dma = [&](int ch) {
        const unsigned short* src = gBbt + ch * 8192 + w * 2048 + lane * 8;
        unsigned short* dst = &sB[ch & 1][w * 2048];        // wave-uniform base
#pragma unroll
        for (int it = 0; it < 4; ++it)
            __builtin_amdgcn_global_load_lds(
                (const __attribute__((address_space(1))) unsigned int*)(src + it * 512),
                (__attribute__((address_space(3))) unsigned int*)(dst + it * 512),
                16, 0, 0);
    };
    auto make_afr = [&](int ch, bf16x8* afr) {
        const int k0 = ch * 128;
        const uint4 ab = *(const uint4*)&abRow[ch * 4];
        const unsigned int abw[4] = {ab.x, ab.y, ab.z, ab.w};
#pragma unroll
        for (int ks = 0; ks < 4; ++ks) {
            const int jb = k0 + ks * 32 + q * 8;
            const uint4 xa = *(const uint4*)&sXP[jb];       // cols jb..jb+3
            const uint4 xb = *(const uint4*)&sXP[jb + 4];   // cols jb+4..jb+7
            const unsigned int xp[8] = {xa.x, xa.y, xa.z, xa.w,
                                        xb.x, xb.y, xb.z, xb.w};
            const unsigned int mb = (abw[ks] >> (q * 8)) & 0xFFu;
            union { unsigned int u[4]; bf16x8 v; } A;
#pragma unroll
            for (int jp = 0; jp < 4; ++jp) {
                const float X1a = __uint_as_float(xp[2 * jp] << 16);
                const float X2a = __uint_as_float(xp[2 * jp] & 0xFFFF0000u);
                const float X1b = __uint_as_float(xp[2 * jp + 1] << 16);
                const float X2b = __uint_as_float(xp[2 * jp + 1] & 0xFFFF0000u);
                const bool sa = X1a > T;
                const bool sb = X1b > T;
                float p0 = (sa ? X1a : X2a) * (sa ? E1 : E2);
                float p1 = (sb ? X1b : X2b) * (sb ? E1 : E2);
                p0 = ((mb >> (2 * jp)) & 1u)     ? p0 : 0.f;
                p1 = ((mb >> (2 * jp + 1)) & 1u) ? p1 : 0.f;
                lsum += p0 + p1;
                A.u[jp] = __builtin_amdgcn_perm(
                    __float_as_uint(p1) + 0x8000u,
                    __float_as_uint(p0) + 0x8000u, 0x07060302u);
            }
            afr[ks] = A.v;
        }
    };
    auto mfma_chunk = [&](int ch, const bf16x8* afr) {
        const char* src = (const char*)sB[ch & 1];
        const int slotoff = ((q + m15) & 3) * 16;           // XOR-swizzled slot
#pragma unroll
        for (int ct = 0; ct < 4; ++ct)
#pragma unroll
            for (int ks = 0; ks < 4; ++ks) {
                const bf16x8 bb = *(const bf16x8*)
                    (src + ks * 4096 + (ct * 16 + m15) * 64 + slotoff);
                acc[ct] = __builtin_amdgcn_mfma_f32_16x16x32_bf16(
                    afr[ks], bb, acc[ct], 0, 0, 0);
            }
    };

    bf16x8 afrA[4], afrB[4];

    dma(0);
    make_afr(0, afrA);
    __syncthreads();            // vmcnt drain -> sB[0] ready

    for (int ch = 0; ch < 8; ++ch) {
        bf16x8* cur = (ch & 1) ? afrB : afrA;
        bf16x8* nxt = (ch & 1) ? afrA : afrB;
        if (ch < 7) {
            dma(ch + 1);
            mfma_chunk(ch, cur);
            make_afr(ch + 1, nxt);
            __syncthreads();    // drains DMA(ch+1); covered by MFMA + select work
        } else {
            mfma_chunk(ch, cur);
        }
    }

    // row denominators: lanes {l, l^16, l^32, l^48} share row m15
    lsum += __shfl_xor(lsum, 16, 64);
    lsum += __shfl_xor(lsum, 32, 64);

    float rinv[4];
#pragma unroll
    for (int reg = 0; reg < 4; ++reg)
        rinv[reg] = 1.f / __shfl(lsum, q * 4 + reg, 64);

#pragma unroll
    for (int ct = 0; ct < 4; ++ct) {
#pragma unroll
        for (int reg = 0; reg < 4; ++reg) {
            float h = acc[ct][reg] * rinv[reg];
            h = (h > 0.f) ? h : (exp2f(h * L2E) - 1.f);     // ELU
            out[(size_t)(bt * N + i0 + w * 16 + q * 4 + reg) * F + ct * 16 + m15] = h;
        }
    }
}

// ------------------------------------------------------------------
extern "C" void kernel_launch(void* const* d_in, const int* in_sizes, int n_in,
                              void* d_out, int out_size, void* d_ws, size_t ws_size,
                              hipStream_t stream)
{
    const float* x    = (const float*)d_in[0];
    const int*   adj  = (const int*)  d_in[1];
    const float* emb1 = (const float*)d_in[2];
    const float* emb2 = (const float*)d_in[3];
    const float* W    = (const float*)d_in[4];
    const float* a    = (const float*)d_in[5];
    const float* a2   = (const float*)d_in[6];
    float* out = (float*)d_out;

    unsigned short* WhSw = (unsigned short*)d_ws;             // 6.29 MB
    float* s1 = (float*)(WhSw + (size_t)BT * 65536);
    float* s2 = s1 + BT * N;
    float* f1 = s2 + BT * N;
    float* f2 = f1 + N;
    unsigned int* adjBits = (unsigned int*)(f2 + N);          // 128 KB

    hipLaunchKernelGGL(k_proj_misc, dim3(900), dim3(256), 0, stream,
                       x, W, a, adj, emb1, emb2, a2, WhSw, s1, s2, adjBits, f1, f2);
    hipLaunchKernelGGL(k_attn, dim3(BT * 16), dim3(256), 0, stream,
                       adjBits, WhSw, s1, s2, f1, f2, out);
}

// Round 11
// 120.443 us; speedup vs baseline: 1.0381x; 1.0381x over previous
//
#include <hip/hip_runtime.h>
#include <hip/hip_bf16.h>
#include <math.h>

#define BT 48
#define N 1024
#define F 64
#define CIN 64
#define EM 16
#define LRELU_A 0.2f
#define L2E 1.4426950408889634f

typedef short bf16x8 __attribute__((ext_vector_type(8)));   // 8 bf16 = 4 VGPRs
typedef float f32x4  __attribute__((ext_vector_type(4)));

// exact RTNE float->bf16 bits (k_proj only, off hot path)
__device__ __forceinline__ unsigned short f2bf(float f) {
    unsigned int u = __float_as_uint(f);
    return (unsigned short)((u + 0x7FFFu + ((u >> 16) & 1u)) >> 16);
}

// ------------------------------------------------------------------
// k_proj_misc (proven since round 7):
//  blocks 0..767: Wh row-block -> WhSw bf16 [bt][nb32][f][slot][j],
//    slot=(q+f)&3 XOR swizzle; + s1/s2 wave reductions.
//  blocks 768..895: adj bit-pack. blocks 896..899: f1/f2.
// ------------------------------------------------------------------
__global__ __launch_bounds__(256) void k_proj_misc(
    const float* __restrict__ x, const float* __restrict__ W,
    const float* __restrict__ a,
    const int* __restrict__ adj,
    const float* __restrict__ emb1, const float* __restrict__ emb2,
    const float* __restrict__ a2,
    unsigned short* __restrict__ WhSw,
    float* __restrict__ s1, float* __restrict__ s2,
    unsigned int* __restrict__ adjBits,
    float* __restrict__ f1, float* __restrict__ f2)
{
    const int tid = threadIdx.x;
    const int b   = blockIdx.x;

    if (b >= 768) {
        if (b < 896) {
            const int idx = (b - 768) * 256 + tid;
            const int r = idx >> 5, w32 = idx & 31;
            const int* p = adj + (size_t)r * N + w32 * 32;
            unsigned int m = 0;
#pragma unroll
            for (int j = 0; j < 32; ++j) m |= (p[j] > 0 ? 1u : 0u) << j;
            adjBits[idx] = m;
        } else {
            const int n = (b - 896) * 256 + tid;
            if (n < N) {
                float v1 = 0.f, v2 = 0.f;
#pragma unroll
                for (int k = 0; k < EM; ++k) {
                    v1 = fmaf(emb1[n * EM + k], a2[k], v1);
                    v2 = fmaf(emb2[n * EM + k], a2[EM + k], v2);
                }
                f1[n] = v1; f2[n] = v2;
            }
        }
        return;
    }

    __shared__ __align__(16) float sx[64 * 64];
    __shared__ __align__(16) float sWT[64 * 68];
    __shared__ __align__(16) unsigned short sT[64 * 80];

    const int bt  = b >> 4;
    const int n0  = (b & 15) * 64;
    const size_t grow = (size_t)bt * N + n0;

    {
        const float4* xv = (const float4*)(x + grow * CIN);
        float4* sxv = (float4*)sx;
        for (int i = tid; i < 64 * CIN / 4; i += 256) sxv[i] = xv[i];
        for (int i = tid; i < CIN * F; i += 256)
            sWT[(i & 63) * 68 + (i >> 6)] = W[i];
    }
    __syncthreads();

    const int f = tid & 63;
    const int w = tid >> 6;
    const float a1 = a[f], a2c = a[F + f];

    float acc[16];
#pragma unroll
    for (int t = 0; t < 16; ++t) acc[t] = 0.f;

    for (int cb = 0; cb < CIN; cb += 4) {
        const float4 wv = *(const float4*)&sWT[f * 68 + cb];
#pragma unroll
        for (int t = 0; t < 16; ++t) {
            const float4 xv = *(const float4*)&sx[(w * 16 + t) * 64 + cb];
            acc[t] = fmaf(xv.x, wv.x, acc[t]);
            acc[t] = fmaf(xv.y, wv.y, acc[t]);
            acc[t] = fmaf(xv.z, wv.z, acc[t]);
            acc[t] = fmaf(xv.w, wv.w, acc[t]);
        }
    }

#pragma unroll
    for (int t = 0; t < 16; ++t) {
        float v1 = acc[t] * a1;
        float v2 = acc[t] * a2c;
#pragma unroll
        for (int off = 32; off >= 1; off >>= 1) {
            v1 += __shfl_xor(v1, off, 64);
            v2 += __shfl_xor(v2, off, 64);
        }
        if (f == 0) {
            s1[grow + w * 16 + t] = v1;
            s2[grow + w * 16 + t] = v2;
        }
        sT[f * 80 + w * 16 + t] = f2bf(acc[t]);
    }
    __syncthreads();

    {
        const int ff = tid >> 2, q = tid & 3;
        const int slot = (q + ff) & 3;
        const int nb0 = (b & 15) * 2;
#pragma unroll
        for (int nbL = 0; nbL < 2; ++nbL) {
            const size_t dst = ((size_t)(bt * 32 + nb0 + nbL) * 64 + ff) * 32 + slot * 8;
            *(uint4*)&WhSw[dst] = *(const uint4*)&sT[ff * 80 + nbL * 32 + q * 8];
        }
    }
}

// ------------------------------------------------------------------
// k_attn (round-9 exact — best measured config, 120.3 us total):
// DMA double-buffer, XOR-swizzled B, single barrier/chunk, FACTORIZED
// softmax: pos branch exp2(r+c-m^)=E1*X1 (X1=2^c), neg branch
// =E2*X2 (X2=2^.2c), select via X1>T (T=2^-r). X1/X2 staged f32 in
// LDS (2048 exps/block); inner loop has NO transcendentals.
// ------------------------------------------------------------------
__global__ __launch_bounds__(256, 3) void k_attn(
    const unsigned int* __restrict__ adjBits,
    const unsigned short* __restrict__ WhSw,
    const float* __restrict__ s1, const float* __restrict__ s2,
    const float* __restrict__ f1v, const float* __restrict__ f2v,
    float* __restrict__ out)
{
    __shared__ __align__(16) float sX1[N];                  // 2^c   (scaled domain)
    __shared__ __align__(16) float sX2[N];                  // 2^.2c
    __shared__ __align__(16) unsigned short sB[2][8192];    // 2 x 16 KB
    __shared__ float sWmax[4];

    const int tid  = threadIdx.x;
    const int xcd = blockIdx.x & 7;                         // XCD swizzle: 6 bt/XCD
    const int idx = blockIdx.x >> 3;
    const int bt  = xcd * 6 + (idx >> 4);
    const int i0  = (idx & 15) * 64;
    const int lane = tid & 63;
    const int w    = tid >> 6;
    const int q    = lane >> 4;
    const int m15  = lane & 15;

    // stage X1/X2 and track block max of c (scaled by log2e)
    float cmax = -1e30f;
    for (int j = tid; j < N; j += 256) {
        const float c = (s2[bt * N + j] + f2v[j]) * L2E;
        sX1[j] = exp2f(c);
        sX2[j] = exp2f(LRELU_A * c);
        cmax = fmaxf(cmax, c);
    }
#pragma unroll
    for (int off = 32; off >= 1; off >>= 1) cmax = fmaxf(cmax, __shfl_xor(cmax, off, 64));
    if (lane == 0) sWmax[w] = cmax;
    __syncthreads();
    const float mx = fmaxf(fmaxf(sWmax[0], sWmax[1]), fmaxf(sWmax[2], sWmax[3]));

    const int growq = i0 + w * 16 + m15;
    const float r    = (s1[bt * N + growq] + f1v[growq]) * L2E;   // scaled domain
    const float smx  = r + mx;
    const float mhat = fmaxf(smx, LRELU_A * smx);           // >= every scaled e in row
    const float E1 = exp2f(r - mhat);
    const float E2 = exp2f(LRELU_A * r - mhat);
    const float T  = exp2f(-r);                             // X1 > T <=> c > -r
    float lsum = 0.f;

    const unsigned int* abRow = adjBits + growq * 32;
    const unsigned short* gBbt = WhSw + (size_t)bt * 65536;

    f32x4 acc[4];
#pragma unroll
    for (int ct = 0; ct < 4; ++ct)
#pragma unroll
        for (int e = 0; e < 4; ++e) acc[ct][e] = 0.f;

    auto dma = [&](int ch) {
        const unsigned short* src = gBbt + ch * 8192 + w * 2048 + lane * 8;
        unsigned short* dst = &sB[ch & 1][w * 2048];        // wave-uniform base
#pragma unroll
        for (int it = 0; it < 4; ++it)
            __builtin_amdgcn_global_load_lds(
                (const __attribute__((address_space(1))) unsigned int*)(src + it * 512),
                (__attribute__((address_space(3))) unsigned int*)(dst + it * 512),
                16, 0, 0);
    };
    auto make_afr = [&](int ch, bf16x8* afr) {
        const int k0 = ch * 128;
        const uint4 ab = *(const uint4*)&abRow[ch * 4];
        const unsigned int abw[4] = {ab.x, ab.y, ab.z, ab.w};
#pragma unroll
        for (int ks = 0; ks < 4; ++ks) {
            const int jb = k0 + ks * 32 + q * 8;
            const float4 x1a = *(const float4*)&sX1[jb];
            const float4 x1b = *(const float4*)&sX1[jb + 4];
            const float4 x2a = *(const float4*)&sX2[jb];
            const float4 x2b = *(const float4*)&sX2[jb + 4];
            const float X1[8] = {x1a.x, x1a.y, x1a.z, x1a.w, x1b.x, x1b.y, x1b.z, x1b.w};
            const float X2[8] = {x2a.x, x2a.y, x2a.z, x2a.w, x2b.x, x2b.y, x2b.z, x2b.w};
            const unsigned int mb = (abw[ks] >> (q * 8)) & 0xFFu;
            union { unsigned int u[4]; bf16x8 v; } A;
#pragma unroll
            for (int jp = 0; jp < 4; ++jp) {
                const bool s0 = X1[2 * jp]     > T;
                const bool s1b = X1[2 * jp + 1] > T;
                float p0 = (s0  ? X1[2 * jp]     : X2[2 * jp])     * (s0  ? E1 : E2);
                float p1 = (s1b ? X1[2 * jp + 1] : X2[2 * jp + 1]) * (s1b ? E1 : E2);
                p0 = ((mb >> (2 * jp)) & 1u)     ? p0 : 0.f;
                p1 = ((mb >> (2 * jp + 1)) & 1u) ? p1 : 0.f;
                lsum += p0 + p1;
                A.u[jp] = __builtin_amdgcn_perm(
                    __float_as_uint(p1) + 0x8000u,
                    __float_as_uint(p0) + 0x8000u, 0x07060302u);
            }
            afr[ks] = A.v;
        }
    };
    auto mfma_chunk = [&](int ch, const bf16x8* afr) {
        const char* src = (const char*)sB[ch & 1];
        const int slotoff = ((q + m15) & 3) * 16;           // XOR-swizzled slot
#pragma unroll
        for (int ct = 0; ct < 4; ++ct)
#pragma unroll
            for (int ks = 0; ks < 4; ++ks) {
                const bf16x8 bb = *(const bf16x8*)
                    (src + ks * 4096 + (ct * 16 + m15) * 64 + slotoff);
                acc[ct] = __builtin_amdgcn_mfma_f32_16x16x32_bf16(
                    afr[ks], bb, acc[ct], 0, 0, 0);
            }
    };

    bf16x8 afrA[4], afrB[4];

    dma(0);
    make_afr(0, afrA);
    __syncthreads();            // vmcnt drain -> sB[0] ready

    for (int ch = 0; ch < 8; ++ch) {
        bf16x8* cur = (ch & 1) ? afrB : afrA;
        bf16x8* nxt = (ch & 1) ? afrA : afrB;
        if (ch < 7) {
            dma(ch + 1);
            mfma_chunk(ch, cur);
            make_afr(ch + 1, nxt);
            __syncthreads();    // drains DMA(ch+1); covered by MFMA + select work
        } else {
            mfma_chunk(ch, cur);
        }
    }

    // row denominators: lanes {l, l^16, l^32, l^48} share row m15
    lsum += __shfl_xor(lsum, 16, 64);
    lsum += __shfl_xor(lsum, 32, 64);

    float rinv[4];
#pragma unroll
    for (int reg = 0; reg < 4; ++reg)
        rinv[reg] = 1.f / __shfl(lsum, q * 4 + reg, 64);

#pragma unroll
    for (int ct = 0; ct < 4; ++ct) {
#pragma unroll
        for (int reg = 0; reg < 4; ++reg) {
            float h = acc[ct][reg] * rinv[reg];
            h = (h > 0.f) ? h : (__expf(h) - 1.f);          // ELU
            out[(size_t)(bt * N + i0 + w * 16 + q * 4 + reg) * F + ct * 16 + m15] = h;
        }
    }
}

// ------------------------------------------------------------------
extern "C" void kernel_launch(void* const* d_in, const int* in_sizes, int n_in,
                              void* d_out, int out_size, void* d_ws, size_t ws_size,
                              hipStream_t stream)
{
    const float* x    = (const float*)d_in[0];
    const int*   adj  = (const int*)  d_in[1];
    const float* emb1 = (const float*)d_in[2];
    const float* emb2 = (const float*)d_in[3];
    const float* W    = (const float*)d_in[4];
    const float* a    = (const float*)d_in[5];
    const float* a2   = (const float*)d_in[6];
    float* out = (float*)d_out;

    unsigned short* WhSw = (unsigned short*)d_ws;             // 6.29 MB
    float* s1 = (float*)(WhSw + (size_t)BT * 65536);
    float* s2 = s1 + BT * N;
    float* f1 = s2 + BT * N;
    float* f2 = f1 + N;
    unsigned int* adjBits = (unsigned int*)(f2 + N);          // 128 KB

    hipLaunchKernelGGL(k_proj_misc, dim3(900), dim3(256), 0, stream,
                       x, W, a, adj, emb1, emb2, a2, WhSw, s1, s2, adjBits, f1, f2);
    hipLaunchKernelGGL(k_attn, dim3(BT * 16), dim3(256), 0, stream,
                       adjBits, WhSw, s1, s2, f1, f2, out);
}